// Round 4
// baseline (533.584 us; speedup 1.0000x reference)
//
#include <hip/hip_runtime.h>
#include <hip/hip_bf16.h>
#include <stdint.h>

#define D_DIM 1024
#define NH 16
#define DHD 64
#define SEQ 64
#define NBATCH 256
#define M_TOT 16384            // NBATCH*SEQ
#define ATT_SCALE 0.125f       // 64^-0.5
#define LN_EPS 1e-5f

typedef __attribute__((ext_vector_type(8))) short bf16x8;
typedef __attribute__((ext_vector_type(4))) float f32x4;

__device__ __forceinline__ short f2bf(float f) {
  union { __hip_bfloat16 h; short s; } c; c.h = __float2bfloat16(f);
  return c.s;
}

__device__ __forceinline__ bf16x8 cvt8(float4 a, float4 b) {
  bf16x8 r;
  r[0] = f2bf(a.x); r[1] = f2bf(a.y); r[2] = f2bf(a.z); r[3] = f2bf(a.w);
  r[4] = f2bf(b.x); r[5] = f2bf(b.y); r[6] = f2bf(b.z); r[7] = f2bf(b.w);
  return r;
}

// async global->LDS, 16B/lane. LDS dest = wave-uniform base + lane*16.
__device__ __forceinline__ void cp16(const void* g, void* l) {
  __builtin_amdgcn_global_load_lds(
      (const __attribute__((address_space(1))) uint32_t*)g,
      (__attribute__((address_space(3))) uint32_t*)l, 16, 0, 0);
}

// ---------------------------------------------------------------------------
// Kernel 0: convert Wq,Wk,Wv,Wo (fp32) -> stacked bf16 Wall[4][1024][1024].
// ---------------------------------------------------------------------------
__global__ void conv_w(const float* __restrict__ Wq, const float* __restrict__ Wk,
                       const float* __restrict__ Wv, const float* __restrict__ Wo,
                       __hip_bfloat16* __restrict__ Wall) {
  const size_t idx8 = ((size_t)blockIdx.x * 256 + threadIdx.x) * 8;
  const int z = (int)(idx8 >> 20);
  const size_t off = idx8 & ((1u << 20) - 1);
  const float* src = (z == 0) ? Wq : (z == 1) ? Wk : (z == 2) ? Wv : Wo;
  float4 a = ((const float4*)(src + off))[0];
  float4 b = ((const float4*)(src + off))[1];
  *(bf16x8*)((short*)Wall + idx8) = cvt8(a, b);
}

// ---------------------------------------------------------------------------
// Kernel 1: QKV projection. A fp32 staged via global_load_lds into two
// [128][16] fp32 half-tiles (64B row stride); W from pre-converted bf16.
// C[m,n] = sum_k A[m,k]*W[n,k]. 128x128 tile, BK=32, 4 waves (2x2).
// z<2 -> out [B,H,seq,dh]; z==2 -> out [B,H,dh,seq] (V transposed).
// ---------------------------------------------------------------------------
__global__ void gemm_qkv(const float* __restrict__ A,
                         const __hip_bfloat16* __restrict__ Wall,
                         __hip_bfloat16* __restrict__ Qw,
                         __hip_bfloat16* __restrict__ Kw,
                         __hip_bfloat16* __restrict__ Vtw) {
  __shared__ __align__(16) float As0[128 * 16];          // k 0..15   (8KB)
  __shared__ __align__(16) float As1[128 * 16];          // k 16..31  (8KB)
  __shared__ __align__(16) __hip_bfloat16 Bs[128 * 32];  // bf16      (8KB)
  const int tid = threadIdx.x;
  const int lane = tid & 63;
  const int wave = tid >> 6;
  const int l16 = lane & 15, kq = lane >> 4;       // kq in 0..3
  const int m0 = blockIdx.x * 128, n0 = blockIdx.y * 128;
  const int z = blockIdx.z;
  const __hip_bfloat16* Bm = Wall + (size_t)z * D_DIM * D_DIM;
  const int wr = (wave >> 1) * 64, wc = (wave & 1) * 64;

  f32x4 acc[4][4] = {};

  for (int kk = 0; kk < D_DIM; kk += 32) {
#pragma unroll
    for (int i = 0; i < 2; ++i) {
      int chunk = i * 256 + tid;                   // 0..511
      int ldsb = (i * 256 + wave * 64) * 16;       // wave-uniform byte base
      {  // As0: chunk = 4 fp32, row r = chunk>>2, col c4 = (chunk&3)*4
        int r = chunk >> 2, c4 = (chunk & 3) << 2;
        cp16(A + (size_t)(m0 + r) * D_DIM + kk + c4, (char*)As0 + ldsb);
        cp16(A + (size_t)(m0 + r) * D_DIM + kk + 16 + c4, (char*)As1 + ldsb);
      }
      {  // Bs: chunk = 8 bf16, row r = chunk>>2, col c8 = (chunk&3)*8
        int r = chunk >> 2, c8 = (chunk & 3) << 3;
        cp16(Bm + (size_t)(n0 + r) * D_DIM + kk + c8, (char*)Bs + ldsb);
      }
    }
    __syncthreads();
    bf16x8 af[4], bfr[4];
    const float* Ah = (kq < 2) ? As0 : As1;
    const int ko = (kq & 1) * 8;
#pragma unroll
    for (int i = 0; i < 4; ++i) {
      const float4* p = (const float4*)(Ah + (wr + i * 16 + l16) * 16 + ko);
      af[i] = cvt8(p[0], p[1]);
    }
#pragma unroll
    for (int j = 0; j < 4; ++j)
      bfr[j] = *(const bf16x8*)((const short*)Bs + (wc + j * 16 + l16) * 32 + kq * 8);
#pragma unroll
    for (int i = 0; i < 4; ++i)
#pragma unroll
      for (int j = 0; j < 4; ++j)
        acc[i][j] = __builtin_amdgcn_mfma_f32_16x16x32_bf16(af[i], bfr[j], acc[i][j], 0, 0, 0);
    __syncthreads();
  }

  __hip_bfloat16* outp = (z == 0) ? Qw : (z == 1) ? Kw : Vtw;
#pragma unroll
  for (int i = 0; i < 4; ++i) {
#pragma unroll
    for (int r = 0; r < 4; ++r) {
      int gm = m0 + wr + i * 16 + kq * 4 + r;      // token index
      int b = gm >> 6, ks = gm & 63;
#pragma unroll
      for (int j = 0; j < 4; ++j) {
        int gn = n0 + wc + j * 16 + l16;           // feature index
        int h = gn >> 6, dh = gn & 63;
        size_t idx = (z < 2)
            ? ((size_t)(b * NH + h) * SEQ + ks) * DHD + dh
            : ((size_t)(b * NH + h) * DHD + dh) * SEQ + ks;
        outp[idx] = __float2bfloat16(acc[i][j][r]);
      }
    }
  }
}

// ---------------------------------------------------------------------------
// Kernel 2: attention, one block per (b,h). All-bf16 workspace I/O.
// Q,K: [64 seq][64 dh]; Vt: [64 dh][64 seq]. O written in-place into Q slice.
// ---------------------------------------------------------------------------
__global__ void attn_k(__hip_bfloat16* Qw,                 // in: Q, out: O (aliased)
                       const __hip_bfloat16* __restrict__ Kw,
                       const __hip_bfloat16* __restrict__ Vtw,
                       const int* __restrict__ mask) {
  __shared__ __align__(16) __hip_bfloat16 Qs[4096];
  __shared__ __align__(16) __hip_bfloat16 Ks[4096];
  __shared__ __align__(16) __hip_bfloat16 Vs[4096];
  __shared__ __align__(16) __hip_bfloat16 Ps[4096];
  const int tid = threadIdx.x;
  const int lane = tid & 63;
  const int wave = tid >> 6;
  const int l16 = lane & 15, kq = lane >> 4;
  const int w16 = wave * 16;
  const size_t base = (size_t)blockIdx.x * 4096;

#pragma unroll
  for (int i = 0; i < 2; ++i) {
    int chunk = i * 256 + tid;
    int ldsb = (i * 256 + wave * 64) * 16;
    cp16(Qw + base + chunk * 8, (char*)Qs + ldsb);
    cp16(Kw + base + chunk * 8, (char*)Ks + ldsb);
    cp16(Vtw + base + chunk * 8, (char*)Vs + ldsb);
  }
  __syncthreads();

  // S = Q @ K^T  (wave handles 16 query rows x 64 key cols)
  f32x4 accS[4] = {};
#pragma unroll
  for (int kk = 0; kk < 64; kk += 32) {
    bf16x8 a = *(const bf16x8*)((const short*)Qs + (w16 + l16) * 64 + kk + kq * 8);
#pragma unroll
    for (int j = 0; j < 4; ++j) {
      bf16x8 b = *(const bf16x8*)((const short*)Ks + (j * 16 + l16) * 64 + kk + kq * 8);
      accS[j] = __builtin_amdgcn_mfma_f32_16x16x32_bf16(a, b, accS[j], 0, 0, 0);
    }
  }

  // row softmax: row q = w16 + kq*4 + r, col s = j*16 + l16
#pragma unroll
  for (int r = 0; r < 4; ++r) {
    float sv[4];
    float m = -1e30f;
#pragma unroll
    for (int j = 0; j < 4; ++j) { sv[j] = accS[j][r] * ATT_SCALE; m = fmaxf(m, sv[j]); }
#pragma unroll
    for (int off = 1; off < 16; off <<= 1) m = fmaxf(m, __shfl_xor(m, off, 64));
    float s = 0.f;
#pragma unroll
    for (int j = 0; j < 4; ++j) { sv[j] = __expf(sv[j] - m); s += sv[j]; }
#pragma unroll
    for (int off = 1; off < 16; off <<= 1) s += __shfl_xor(s, off, 64);
    float inv = 1.0f / s;
    int row = w16 + kq * 4 + r;
#pragma unroll
    for (int j = 0; j < 4; ++j)
      Ps[row * 64 + j * 16 + l16] = __float2bfloat16(sv[j] * inv);
  }
  __syncthreads();

  // O = P @ V   (Vs holds V^T: row d, col s)
  f32x4 accO[4] = {};
#pragma unroll
  for (int kk = 0; kk < 64; kk += 32) {
    bf16x8 a = *(const bf16x8*)((const short*)Ps + (w16 + l16) * 64 + kk + kq * 8);
#pragma unroll
    for (int j = 0; j < 4; ++j) {
      bf16x8 b = *(const bf16x8*)((const short*)Vs + (j * 16 + l16) * 64 + kk + kq * 8);
      accO[j] = __builtin_amdgcn_mfma_f32_16x16x32_bf16(a, b, accO[j], 0, 0, 0);
    }
  }

  // write O into the (b,h) slice of Qw: layout [b][h][seq][dh]
  const int b = blockIdx.x >> 4;
#pragma unroll
  for (int r = 0; r < 4; ++r) {
    int q = w16 + kq * 4 + r;
    float mk = mask[b * SEQ + q] ? 1.0f : 0.0f;   // post-softmax query-row mask
#pragma unroll
    for (int j = 0; j < 4; ++j) {
      int d = j * 16 + l16;
      Qw[base + q * DHD + d] = __float2bfloat16(accO[j][r] * mk);
    }
  }
}

// ---------------------------------------------------------------------------
// Kernel 3: O projection + gated residual. Hf(fp32) = hidden + mask[m]*(O @ Wo^T)
// O bf16 in [B,H,seq,dh]; Wo from stacked bf16 (z=3). Pure-bf16 global_load_lds.
// ---------------------------------------------------------------------------
__global__ void gemm_o(const __hip_bfloat16* __restrict__ Ow,   // [B,H,seq,dh]
                       const __hip_bfloat16* __restrict__ WoB,  // bf16 [1024][1024]
                       const float* __restrict__ hidden,
                       const int* __restrict__ mask,
                       float* __restrict__ Hf) {
  __shared__ __align__(16) __hip_bfloat16 As[128 * 32];
  __shared__ __align__(16) __hip_bfloat16 Bs[128 * 32];
  const int tid = threadIdx.x;
  const int lane = tid & 63;
  const int wave = tid >> 6;
  const int l16 = lane & 15, kq = lane >> 4;
  const int m0 = blockIdx.x * 128, n0 = blockIdx.y * 128;
  const int wr = (wave >> 1) * 64, wc = (wave & 1) * 64;

  f32x4 acc[4][4] = {};

  for (int kk = 0; kk < D_DIM; kk += 32) {
#pragma unroll
    for (int i = 0; i < 2; ++i) {
      int chunk = i * 256 + tid;
      int r = chunk >> 2, c8 = (chunk & 3) << 3;
      int ldsb = (i * 256 + wave * 64) * 16;
      // A element: token t = m0+r, feature f = kk+c8 (8 contiguous, same head)
      int t = m0 + r, f = kk + c8;
      int b = t >> 6, s = t & 63, h = f >> 6, dh = f & 63;
      cp16(Ow + ((size_t)((b << 4) + h) << 12) + (s << 6) + dh, (char*)As + ldsb);
      cp16(WoB + (size_t)(n0 + r) * D_DIM + kk + c8, (char*)Bs + ldsb);
    }
    __syncthreads();
    bf16x8 af[4], bfr[4];
#pragma unroll
    for (int i = 0; i < 4; ++i)
      af[i] = *(const bf16x8*)((const short*)As + (wr + i * 16 + l16) * 32 + kq * 8);
#pragma unroll
    for (int j = 0; j < 4; ++j)
      bfr[j] = *(const bf16x8*)((const short*)Bs + (wc + j * 16 + l16) * 32 + kq * 8);
#pragma unroll
    for (int i = 0; i < 4; ++i)
#pragma unroll
      for (int j = 0; j < 4; ++j)
        acc[i][j] = __builtin_amdgcn_mfma_f32_16x16x32_bf16(af[i], bfr[j], acc[i][j], 0, 0, 0);
    __syncthreads();
  }

#pragma unroll
  for (int i = 0; i < 4; ++i) {
#pragma unroll
    for (int r = 0; r < 4; ++r) {
      int gm = m0 + wr + i * 16 + kq * 4 + r;
      float mk = mask[gm] ? 1.0f : 0.0f;
#pragma unroll
      for (int j = 0; j < 4; ++j) {
        int gn = n0 + wc + j * 16 + l16;
        size_t idx = (size_t)gm * D_DIM + gn;
        Hf[idx] = hidden[idx] + mk * acc[i][j][r];
      }
    }
  }
}

// ---------------------------------------------------------------------------
// Kernel 4: LayerNorm over D=1024, fp32 in/out. One row/block, 128 thr x 8.
// ---------------------------------------------------------------------------
__global__ void ln_k(const float* __restrict__ Hf,
                     const float* __restrict__ gamma,
                     const float* __restrict__ beta,
                     float* __restrict__ out) {
  __shared__ float red[4];
  const int row = blockIdx.x, tid = threadIdx.x;
  const int wave = tid >> 6, lane = tid & 63;
  const size_t boff = (size_t)row * D_DIM + tid * 8;

  float4 v0 = ((const float4*)(Hf + boff))[0];
  float4 v1 = ((const float4*)(Hf + boff))[1];
  float f[8] = {v0.x, v0.y, v0.z, v0.w, v1.x, v1.y, v1.z, v1.w};
  float s = 0.f, ss = 0.f;
#pragma unroll
  for (int k = 0; k < 8; ++k) { s += f[k]; ss += f[k] * f[k]; }
#pragma unroll
  for (int off = 1; off < 64; off <<= 1) {
    s += __shfl_xor(s, off, 64);
    ss += __shfl_xor(ss, off, 64);
  }
  if (lane == 0) { red[wave * 2] = s; red[wave * 2 + 1] = ss; }
  __syncthreads();
  s = red[0] + red[2];
  ss = red[1] + red[3];
  const float mu = s * (1.0f / D_DIM);
  const float var = ss * (1.0f / D_DIM) - mu * mu;
  const float rs = rsqrtf(var + LN_EPS);

  float4 g0 = ((const float4*)(gamma + tid * 8))[0];
  float4 g1 = ((const float4*)(gamma + tid * 8))[1];
  float4 b0 = ((const float4*)(beta + tid * 8))[0];
  float4 b1 = ((const float4*)(beta + tid * 8))[1];
  float g[8] = {g0.x, g0.y, g0.z, g0.w, g1.x, g1.y, g1.z, g1.w};
  float bb[8] = {b0.x, b0.y, b0.z, b0.w, b1.x, b1.y, b1.z, b1.w};
  float o[8];
#pragma unroll
  for (int k = 0; k < 8; ++k)
    o[k] = (f[k] - mu) * rs * g[k] + bb[k];
  ((float4*)(out + boff))[0] = make_float4(o[0], o[1], o[2], o[3]);
  ((float4*)(out + boff))[1] = make_float4(o[4], o[5], o[6], o[7]);
}

// ---------------------------------------------------------------------------
extern "C" void kernel_launch(void* const* d_in, const int* in_sizes, int n_in,
                              void* d_out, int out_size, void* d_ws, size_t ws_size,
                              hipStream_t stream) {
  const float* hidden = (const float*)d_in[0];
  const int* mask = (const int*)d_in[1];
  const float* Wq = (const float*)d_in[2];
  const float* Wk = (const float*)d_in[3];
  const float* Wv = (const float*)d_in[4];
  const float* Wo = (const float*)d_in[5];
  const float* gamma = (const float*)d_in[6];
  const float* beta = (const float*)d_in[7];
  float* out = (float*)d_out;

  const size_t SZ = (size_t)M_TOT * D_DIM;      // 16,777,216 elements
  __hip_bfloat16* Qw = (__hip_bfloat16*)d_ws;   // bf16 [B,H,seq,dh]; O in-place
  __hip_bfloat16* Kw = Qw + SZ;                 // bf16 [B,H,seq,dh]
  __hip_bfloat16* Vtw = Kw + SZ;                // bf16 [B,H,dh,seq]
  __hip_bfloat16* Wall = Vtw + SZ;              // bf16 [4][1024][1024] (8.4 MB)
  float* Hf = (float*)Kw;                       // fp32, reuses K+V region (67 MB)
                                                // total ws usage: 109 MB

  conv_w<<<dim3(2048), 256, 0, stream>>>(Wq, Wk, Wv, Wo, Wall);
  gemm_qkv<<<dim3(128, 8, 3), 256, 0, stream>>>(hidden, Wall, Qw, Kw, Vtw);
  attn_k<<<dim3(4096), 256, 0, stream>>>(Qw, Kw, Vtw, mask);
  gemm_o<<<dim3(128, 8), 256, 0, stream>>>(Qw, Wall + 3 * SZ / 16, hidden, mask, Hf);
  ln_k<<<dim3(16384), 128, 0, stream>>>(Hf, gamma, beta, out);
}

// Round 5
// 375.545 us; speedup vs baseline: 1.4208x; 1.4208x over previous
//
#include <hip/hip_runtime.h>
#include <hip/hip_bf16.h>
#include <stdint.h>

#define D_DIM 1024
#define NH 16
#define DHD 64
#define SEQ 64
#define NBATCH 256
#define M_TOT 16384            // NBATCH*SEQ
#define ATT_SCALE 0.125f       // 64^-0.5
#define LN_EPS 1e-5f

typedef __attribute__((ext_vector_type(8))) short bf16x8;
typedef __attribute__((ext_vector_type(4))) float f32x4;

__device__ __forceinline__ short f2bf(float f) {
  union { __hip_bfloat16 h; short s; } c; c.h = __float2bfloat16(f);
  return c.s;
}

__device__ __forceinline__ bf16x8 cvt8(float4 a, float4 b) {
  bf16x8 r;
  r[0] = f2bf(a.x); r[1] = f2bf(a.y); r[2] = f2bf(a.z); r[3] = f2bf(a.w);
  r[4] = f2bf(b.x); r[5] = f2bf(b.y); r[6] = f2bf(b.z); r[7] = f2bf(b.w);
  return r;
}

// async global->LDS, 16B/lane. LDS dest = wave-uniform base + lane*16.
__device__ __forceinline__ void cp16(const void* g, void* l) {
  __builtin_amdgcn_global_load_lds(
      (const __attribute__((address_space(1))) uint32_t*)g,
      (__attribute__((address_space(3))) uint32_t*)l, 16, 0, 0);
}

// ---------------------------------------------------------------------------
// Kernel 0a: convert Wq,Wk,Wv,Wo (fp32) -> stacked bf16 Wall[4][1024][1024].
// ---------------------------------------------------------------------------
__global__ void conv_w(const float* __restrict__ Wq, const float* __restrict__ Wk,
                       const float* __restrict__ Wv, const float* __restrict__ Wo,
                       __hip_bfloat16* __restrict__ Wall) {
  const size_t idx8 = ((size_t)blockIdx.x * 256 + threadIdx.x) * 8;
  const int z = (int)(idx8 >> 20);
  const size_t off = idx8 & ((1u << 20) - 1);
  const float* src = (z == 0) ? Wq : (z == 1) ? Wk : (z == 2) ? Wv : Wo;
  float4 a = ((const float4*)(src + off))[0];
  float4 b = ((const float4*)(src + off))[1];
  *(bf16x8*)((short*)Wall + idx8) = cvt8(a, b);
}

// Kernel 0b: convert hidden (fp32 [M][1024]) -> bf16 Hb.
__global__ void conv_h(const float* __restrict__ H, __hip_bfloat16* __restrict__ Hb) {
  const size_t idx8 = ((size_t)blockIdx.x * 256 + threadIdx.x) * 8;
  float4 a = ((const float4*)(H + idx8))[0];
  float4 b = ((const float4*)(H + idx8))[1];
  *(bf16x8*)((short*)Hb + idx8) = cvt8(a, b);
}

// ---------------------------------------------------------------------------
// Kernel 1a (preferred): pure-bf16 m97-style QKV GEMM. A = Hb (bf16), B = Wall.
// Both staged via global_load_lds width-16 into [128][32] bf16 tiles.
// C[m,n] = sum_k A[m,k]*W[n,k]. 128x128 tile, BK=32, 4 waves (2x2).
// z<2 -> out [B,H,seq,dh]; z==2 -> out [B,H,dh,seq] (V transposed).
// ---------------------------------------------------------------------------
__global__ void gemm_qkv_bf(const __hip_bfloat16* __restrict__ Hb,
                            const __hip_bfloat16* __restrict__ Wall,
                            __hip_bfloat16* __restrict__ Qw,
                            __hip_bfloat16* __restrict__ Kw,
                            __hip_bfloat16* __restrict__ Vtw) {
  __shared__ __align__(16) __hip_bfloat16 As[128 * 32];
  __shared__ __align__(16) __hip_bfloat16 Bs[128 * 32];
  const int tid = threadIdx.x;
  const int lane = tid & 63;
  const int wave = tid >> 6;
  const int l16 = lane & 15, kq = lane >> 4;
  const int m0 = blockIdx.x * 128, n0 = blockIdx.y * 128;
  const int z = blockIdx.z;
  const __hip_bfloat16* Bm = Wall + (size_t)z * D_DIM * D_DIM;
  const int wr = (wave >> 1) * 64, wc = (wave & 1) * 64;

  f32x4 acc[4][4] = {};

  for (int kk = 0; kk < D_DIM; kk += 32) {
#pragma unroll
    for (int i = 0; i < 2; ++i) {
      int chunk = i * 256 + tid;                   // 0..511, 8-elt chunk
      int r = chunk >> 2, c8 = (chunk & 3) << 3;
      int ldsb = (i * 256 + wave * 64) * 16;       // wave-uniform byte base
      cp16(Hb + (size_t)(m0 + r) * D_DIM + kk + c8, (char*)As + ldsb);
      cp16(Bm + (size_t)(n0 + r) * D_DIM + kk + c8, (char*)Bs + ldsb);
    }
    __syncthreads();
    bf16x8 af[4], bfr[4];
#pragma unroll
    for (int i = 0; i < 4; ++i)
      af[i] = *(const bf16x8*)((const short*)As + (wr + i * 16 + l16) * 32 + kq * 8);
#pragma unroll
    for (int j = 0; j < 4; ++j)
      bfr[j] = *(const bf16x8*)((const short*)Bs + (wc + j * 16 + l16) * 32 + kq * 8);
#pragma unroll
    for (int i = 0; i < 4; ++i)
#pragma unroll
      for (int j = 0; j < 4; ++j)
        acc[i][j] = __builtin_amdgcn_mfma_f32_16x16x32_bf16(af[i], bfr[j], acc[i][j], 0, 0, 0);
    __syncthreads();
  }

  __hip_bfloat16* outp = (z == 0) ? Qw : (z == 1) ? Kw : Vtw;
#pragma unroll
  for (int i = 0; i < 4; ++i) {
#pragma unroll
    for (int r = 0; r < 4; ++r) {
      int gm = m0 + wr + i * 16 + kq * 4 + r;
      int b = gm >> 6, ks = gm & 63;
#pragma unroll
      for (int j = 0; j < 4; ++j) {
        int gn = n0 + wc + j * 16 + l16;
        int h = gn >> 6, dh = gn & 63;
        size_t idx = (z < 2)
            ? ((size_t)(b * NH + h) * SEQ + ks) * DHD + dh
            : ((size_t)(b * NH + h) * DHD + dh) * SEQ + ks;
        outp[idx] = __float2bfloat16(acc[i][j][r]);
      }
    }
  }
}

// ---------------------------------------------------------------------------
// Kernel 1b (fallback, small-ws): manual fp32 A staging (round-3 proven) +
// cp16 bf16 B. Same tile/fragment geometry as 1a.
// ---------------------------------------------------------------------------
__global__ void gemm_qkv_hyb(const float* __restrict__ A,
                             const __hip_bfloat16* __restrict__ Wall,
                             __hip_bfloat16* __restrict__ Qw,
                             __hip_bfloat16* __restrict__ Kw,
                             __hip_bfloat16* __restrict__ Vtw) {
  __shared__ __align__(16) __hip_bfloat16 As[128 * 32];
  __shared__ __align__(16) __hip_bfloat16 Bs[128 * 32];
  const int tid = threadIdx.x;
  const int lane = tid & 63;
  const int wave = tid >> 6;
  const int l16 = lane & 15, kq = lane >> 4;
  const int m0 = blockIdx.x * 128, n0 = blockIdx.y * 128;
  const int z = blockIdx.z;
  const __hip_bfloat16* Bm = Wall + (size_t)z * D_DIM * D_DIM;
  const int wr = (wave >> 1) * 64, wc = (wave & 1) * 64;

  f32x4 acc[4][4] = {};

  for (int kk = 0; kk < D_DIM; kk += 32) {
#pragma unroll
    for (int i = 0; i < 2; ++i) {
      int chunk = i * 256 + tid;
      int r = chunk >> 2, c8 = (chunk & 3) << 3;
      int ldsb = (i * 256 + wave * 64) * 16;
      const float* pa = A + (size_t)(m0 + r) * D_DIM + kk + c8;
      float4 a0 = ((const float4*)pa)[0], a1 = ((const float4*)pa)[1];
      *(bf16x8*)((short*)As + chunk * 8) = cvt8(a0, a1);
      cp16(Bm + (size_t)(n0 + r) * D_DIM + kk + c8, (char*)Bs + ldsb);
    }
    __syncthreads();
    bf16x8 af[4], bfr[4];
#pragma unroll
    for (int i = 0; i < 4; ++i)
      af[i] = *(const bf16x8*)((const short*)As + (wr + i * 16 + l16) * 32 + kq * 8);
#pragma unroll
    for (int j = 0; j < 4; ++j)
      bfr[j] = *(const bf16x8*)((const short*)Bs + (wc + j * 16 + l16) * 32 + kq * 8);
#pragma unroll
    for (int i = 0; i < 4; ++i)
#pragma unroll
      for (int j = 0; j < 4; ++j)
        acc[i][j] = __builtin_amdgcn_mfma_f32_16x16x32_bf16(af[i], bfr[j], acc[i][j], 0, 0, 0);
    __syncthreads();
  }

  __hip_bfloat16* outp = (z == 0) ? Qw : (z == 1) ? Kw : Vtw;
#pragma unroll
  for (int i = 0; i < 4; ++i) {
#pragma unroll
    for (int r = 0; r < 4; ++r) {
      int gm = m0 + wr + i * 16 + kq * 4 + r;
      int b = gm >> 6, ks = gm & 63;
#pragma unroll
      for (int j = 0; j < 4; ++j) {
        int gn = n0 + wc + j * 16 + l16;
        int h = gn >> 6, dh = gn & 63;
        size_t idx = (z < 2)
            ? ((size_t)(b * NH + h) * SEQ + ks) * DHD + dh
            : ((size_t)(b * NH + h) * DHD + dh) * SEQ + ks;
        outp[idx] = __float2bfloat16(acc[i][j][r]);
      }
    }
  }
}

// ---------------------------------------------------------------------------
// Kernel 2: attention, one block per (b,h). All-bf16 workspace I/O.
// Q,K: [64 seq][64 dh]; Vt: [64 dh][64 seq]. O written in-place into Q slice.
// ---------------------------------------------------------------------------
__global__ void attn_k(__hip_bfloat16* Qw,                 // in: Q, out: O (aliased)
                       const __hip_bfloat16* __restrict__ Kw,
                       const __hip_bfloat16* __restrict__ Vtw,
                       const int* __restrict__ mask) {
  __shared__ __align__(16) __hip_bfloat16 Qs[4096];
  __shared__ __align__(16) __hip_bfloat16 Ks[4096];
  __shared__ __align__(16) __hip_bfloat16 Vs[4096];
  __shared__ __align__(16) __hip_bfloat16 Ps[4096];
  const int tid = threadIdx.x;
  const int lane = tid & 63;
  const int wave = tid >> 6;
  const int l16 = lane & 15, kq = lane >> 4;
  const int w16 = wave * 16;
  const size_t base = (size_t)blockIdx.x * 4096;

#pragma unroll
  for (int i = 0; i < 2; ++i) {
    int chunk = i * 256 + tid;
    int ldsb = (i * 256 + wave * 64) * 16;
    cp16(Qw + base + chunk * 8, (char*)Qs + ldsb);
    cp16(Kw + base + chunk * 8, (char*)Ks + ldsb);
    cp16(Vtw + base + chunk * 8, (char*)Vs + ldsb);
  }
  __syncthreads();

  // S = Q @ K^T
  f32x4 accS[4] = {};
#pragma unroll
  for (int kk = 0; kk < 64; kk += 32) {
    bf16x8 a = *(const bf16x8*)((const short*)Qs + (w16 + l16) * 64 + kk + kq * 8);
#pragma unroll
    for (int j = 0; j < 4; ++j) {
      bf16x8 b = *(const bf16x8*)((const short*)Ks + (j * 16 + l16) * 64 + kk + kq * 8);
      accS[j] = __builtin_amdgcn_mfma_f32_16x16x32_bf16(a, b, accS[j], 0, 0, 0);
    }
  }

  // row softmax
#pragma unroll
  for (int r = 0; r < 4; ++r) {
    float sv[4];
    float m = -1e30f;
#pragma unroll
    for (int j = 0; j < 4; ++j) { sv[j] = accS[j][r] * ATT_SCALE; m = fmaxf(m, sv[j]); }
#pragma unroll
    for (int off = 1; off < 16; off <<= 1) m = fmaxf(m, __shfl_xor(m, off, 64));
    float s = 0.f;
#pragma unroll
    for (int j = 0; j < 4; ++j) { sv[j] = __expf(sv[j] - m); s += sv[j]; }
#pragma unroll
    for (int off = 1; off < 16; off <<= 1) s += __shfl_xor(s, off, 64);
    float inv = 1.0f / s;
    int row = w16 + kq * 4 + r;
#pragma unroll
    for (int j = 0; j < 4; ++j)
      Ps[row * 64 + j * 16 + l16] = __float2bfloat16(sv[j] * inv);
  }
  __syncthreads();

  // O = P @ V
  f32x4 accO[4] = {};
#pragma unroll
  for (int kk = 0; kk < 64; kk += 32) {
    bf16x8 a = *(const bf16x8*)((const short*)Ps + (w16 + l16) * 64 + kk + kq * 8);
#pragma unroll
    for (int j = 0; j < 4; ++j) {
      bf16x8 b = *(const bf16x8*)((const short*)Vs + (j * 16 + l16) * 64 + kk + kq * 8);
      accO[j] = __builtin_amdgcn_mfma_f32_16x16x32_bf16(a, b, accO[j], 0, 0, 0);
    }
  }

  const int b = blockIdx.x >> 4;
#pragma unroll
  for (int r = 0; r < 4; ++r) {
    int q = w16 + kq * 4 + r;
    float mk = mask[b * SEQ + q] ? 1.0f : 0.0f;
#pragma unroll
    for (int j = 0; j < 4; ++j) {
      int d = j * 16 + l16;
      Qw[base + q * DHD + d] = __float2bfloat16(accO[j][r] * mk);
    }
  }
}

// ---------------------------------------------------------------------------
// Kernel 3: O projection + gated residual. Hf(fp32) = hidden + mask[m]*(O @ Wo^T)
// ---------------------------------------------------------------------------
__global__ void gemm_o(const __hip_bfloat16* __restrict__ Ow,   // [B,H,seq,dh]
                       const __hip_bfloat16* __restrict__ WoB,  // bf16 [1024][1024]
                       const float* __restrict__ hidden,
                       const int* __restrict__ mask,
                       float* __restrict__ Hf) {
  __shared__ __align__(16) __hip_bfloat16 As[128 * 32];
  __shared__ __align__(16) __hip_bfloat16 Bs[128 * 32];
  const int tid = threadIdx.x;
  const int lane = tid & 63;
  const int wave = tid >> 6;
  const int l16 = lane & 15, kq = lane >> 4;
  const int m0 = blockIdx.x * 128, n0 = blockIdx.y * 128;
  const int wr = (wave >> 1) * 64, wc = (wave & 1) * 64;

  f32x4 acc[4][4] = {};

  for (int kk = 0; kk < D_DIM; kk += 32) {
#pragma unroll
    for (int i = 0; i < 2; ++i) {
      int chunk = i * 256 + tid;
      int r = chunk >> 2, c8 = (chunk & 3) << 3;
      int ldsb = (i * 256 + wave * 64) * 16;
      int t = m0 + r, f = kk + c8;
      int b = t >> 6, s = t & 63, h = f >> 6, dh = f & 63;
      cp16(Ow + ((size_t)((b << 4) + h) << 12) + (s << 6) + dh, (char*)As + ldsb);
      cp16(WoB + (size_t)(n0 + r) * D_DIM + kk + c8, (char*)Bs + ldsb);
    }
    __syncthreads();
    bf16x8 af[4], bfr[4];
#pragma unroll
    for (int i = 0; i < 4; ++i)
      af[i] = *(const bf16x8*)((const short*)As + (wr + i * 16 + l16) * 32 + kq * 8);
#pragma unroll
    for (int j = 0; j < 4; ++j)
      bfr[j] = *(const bf16x8*)((const short*)Bs + (wc + j * 16 + l16) * 32 + kq * 8);
#pragma unroll
    for (int i = 0; i < 4; ++i)
#pragma unroll
      for (int j = 0; j < 4; ++j)
        acc[i][j] = __builtin_amdgcn_mfma_f32_16x16x32_bf16(af[i], bfr[j], acc[i][j], 0, 0, 0);
    __syncthreads();
  }

#pragma unroll
  for (int i = 0; i < 4; ++i) {
#pragma unroll
    for (int r = 0; r < 4; ++r) {
      int gm = m0 + wr + i * 16 + kq * 4 + r;
      float mk = mask[gm] ? 1.0f : 0.0f;
#pragma unroll
      for (int j = 0; j < 4; ++j) {
        int gn = n0 + wc + j * 16 + l16;
        size_t idx = (size_t)gm * D_DIM + gn;
        Hf[idx] = hidden[idx] + mk * acc[i][j][r];
      }
    }
  }
}

// ---------------------------------------------------------------------------
// Kernel 4: LayerNorm over D=1024, fp32 in/out. One row/block, 128 thr x 8.
// ---------------------------------------------------------------------------
__global__ void ln_k(const float* __restrict__ Hf,
                     const float* __restrict__ gamma,
                     const float* __restrict__ beta,
                     float* __restrict__ out) {
  __shared__ float red[4];
  const int row = blockIdx.x, tid = threadIdx.x;
  const int wave = tid >> 6, lane = tid & 63;
  const size_t boff = (size_t)row * D_DIM + tid * 8;

  float4 v0 = ((const float4*)(Hf + boff))[0];
  float4 v1 = ((const float4*)(Hf + boff))[1];
  float f[8] = {v0.x, v0.y, v0.z, v0.w, v1.x, v1.y, v1.z, v1.w};
  float s = 0.f, ss = 0.f;
#pragma unroll
  for (int k = 0; k < 8; ++k) { s += f[k]; ss += f[k] * f[k]; }
#pragma unroll
  for (int off = 1; off < 64; off <<= 1) {
    s += __shfl_xor(s, off, 64);
    ss += __shfl_xor(ss, off, 64);
  }
  if (lane == 0) { red[wave * 2] = s; red[wave * 2 + 1] = ss; }
  __syncthreads();
  s = red[0] + red[2];
  ss = red[1] + red[3];
  const float mu = s * (1.0f / D_DIM);
  const float var = ss * (1.0f / D_DIM) - mu * mu;
  const float rs = rsqrtf(var + LN_EPS);

  float4 g0 = ((const float4*)(gamma + tid * 8))[0];
  float4 g1 = ((const float4*)(gamma + tid * 8))[1];
  float4 b0 = ((const float4*)(beta + tid * 8))[0];
  float4 b1 = ((const float4*)(beta + tid * 8))[1];
  float g[8] = {g0.x, g0.y, g0.z, g0.w, g1.x, g1.y, g1.z, g1.w};
  float bb[8] = {b0.x, b0.y, b0.z, b0.w, b1.x, b1.y, b1.z, b1.w};
  float o[8];
#pragma unroll
  for (int k = 0; k < 8; ++k)
    o[k] = (f[k] - mu) * rs * g[k] + bb[k];
  ((float4*)(out + boff))[0] = make_float4(o[0], o[1], o[2], o[3]);
  ((float4*)(out + boff))[1] = make_float4(o[4], o[5], o[6], o[7]);
}

// ---------------------------------------------------------------------------
extern "C" void kernel_launch(void* const* d_in, const int* in_sizes, int n_in,
                              void* d_out, int out_size, void* d_ws, size_t ws_size,
                              hipStream_t stream) {
  const float* hidden = (const float*)d_in[0];
  const int* mask = (const int*)d_in[1];
  const float* Wq = (const float*)d_in[2];
  const float* Wk = (const float*)d_in[3];
  const float* Wv = (const float*)d_in[4];
  const float* Wo = (const float*)d_in[5];
  const float* gamma = (const float*)d_in[6];
  const float* beta = (const float*)d_in[7];
  float* out = (float*)d_out;

  const size_t SZ = (size_t)M_TOT * D_DIM;        // 16,777,216 elements
  const size_t WALL_E = 4ull * D_DIM * D_DIM;     // 4,194,304 elements
  const size_t need_bf = (4 * SZ + WALL_E) * sizeof(__hip_bfloat16);  // ~142.6 MB

  if (ws_size >= need_bf) {
    // bf16 fast path: [Hb][Kw][Qw][Vtw][Wall]; Hf fp32 overlays Hb+Kw.
    __hip_bfloat16* Hb  = (__hip_bfloat16*)d_ws;
    __hip_bfloat16* Kw  = Hb + SZ;
    __hip_bfloat16* Qw  = Hb + 2 * SZ;
    __hip_bfloat16* Vtw = Hb + 3 * SZ;
    __hip_bfloat16* Wall = Hb + 4 * SZ;
    float* Hf = (float*)Hb;                       // dead after gemm_qkv/attn

    conv_w<<<dim3(2048), 256, 0, stream>>>(Wq, Wk, Wv, Wo, Wall);
    conv_h<<<dim3(8192), 256, 0, stream>>>(hidden, Hb);
    gemm_qkv_bf<<<dim3(128, 8, 3), 256, 0, stream>>>(Hb, Wall, Qw, Kw, Vtw);
    attn_k<<<dim3(4096), 256, 0, stream>>>(Qw, Kw, Vtw, mask);
    gemm_o<<<dim3(128, 8), 256, 0, stream>>>(Qw, Wall + 3 * D_DIM * D_DIM,
                                             hidden, mask, Hf);
    ln_k<<<dim3(16384), 128, 0, stream>>>(Hf, gamma, beta, out);
  } else {
    // fallback (109 MB): [Qw][Kw][Vtw][Wall]; Hf fp32 overlays Kw+Vtw.
    __hip_bfloat16* Qw  = (__hip_bfloat16*)d_ws;
    __hip_bfloat16* Kw  = Qw + SZ;
    __hip_bfloat16* Vtw = Qw + 2 * SZ;
    __hip_bfloat16* Wall = Qw + 3 * SZ;
    float* Hf = (float*)Kw;

    conv_w<<<dim3(2048), 256, 0, stream>>>(Wq, Wk, Wv, Wo, Wall);
    gemm_qkv_hyb<<<dim3(128, 8, 3), 256, 0, stream>>>(hidden, Wall, Qw, Kw, Vtw);
    attn_k<<<dim3(4096), 256, 0, stream>>>(Qw, Kw, Vtw, mask);
    gemm_o<<<dim3(128, 8), 256, 0, stream>>>(Qw, Wall + 3 * D_DIM * D_DIM,
                                             hidden, mask, Hf);
    ln_k<<<dim3(16384), 128, 0, stream>>>(Hf, gamma, beta, out);
  }
}

// Round 6
// 362.149 us; speedup vs baseline: 1.4734x; 1.0370x over previous
//
#include <hip/hip_runtime.h>
#include <hip/hip_bf16.h>
#include <stdint.h>

#define D_DIM 1024
#define NH 16
#define DHD 64
#define SEQ 64
#define NBATCH 256
#define M_TOT 16384            // NBATCH*SEQ
#define ATT_SCALE 0.125f       // 64^-0.5
#define LN_EPS 1e-5f

typedef __attribute__((ext_vector_type(8))) short bf16x8;
typedef __attribute__((ext_vector_type(4))) float f32x4;

__device__ __forceinline__ float bf2f(short s) {
  union { uint32_t u; float f; } c;
  c.u = ((uint32_t)(uint16_t)s) << 16;
  return c.f;
}

__device__ __forceinline__ short f2bf(float f) {
  union { __hip_bfloat16 h; short s; } c; c.h = __float2bfloat16(f);
  return c.s;
}

__device__ __forceinline__ bf16x8 cvt8(float4 a, float4 b) {
  bf16x8 r;
  r[0] = f2bf(a.x); r[1] = f2bf(a.y); r[2] = f2bf(a.z); r[3] = f2bf(a.w);
  r[4] = f2bf(b.x); r[5] = f2bf(b.y); r[6] = f2bf(b.z); r[7] = f2bf(b.w);
  return r;
}

// async global->LDS, 16B/lane. LDS dest = wave-uniform base + lane*16.
__device__ __forceinline__ void cp16(const void* g, void* l) {
  __builtin_amdgcn_global_load_lds(
      (const __attribute__((address_space(1))) uint32_t*)g,
      (__attribute__((address_space(3))) uint32_t*)l, 16, 0, 0);
}

// ---------------------------------------------------------------------------
// Kernel 0: fp32 -> bf16 conversion for all weights (stacked Wall) + hidden.
// Flat idx8 space: [Wall: 4M elems][Hb: 16.77M elems].
// ---------------------------------------------------------------------------
__global__ void conv_all(const float* __restrict__ Wq, const float* __restrict__ Wk,
                         const float* __restrict__ Wv, const float* __restrict__ Wo,
                         const float* __restrict__ H,
                         __hip_bfloat16* __restrict__ Wall,
                         __hip_bfloat16* __restrict__ Hb) {
  const size_t idx8 = ((size_t)blockIdx.x * 256 + threadIdx.x) * 8;
  const size_t WE = (size_t)4 * D_DIM * D_DIM;   // 4,194,304
  const float* src;
  __hip_bfloat16* dst;
  if (idx8 < WE) {
    int z = (int)(idx8 >> 20);
    size_t off = idx8 & ((1u << 20) - 1);
    src = ((z == 0) ? Wq : (z == 1) ? Wk : (z == 2) ? Wv : Wo) + off;
    dst = Wall + idx8;
  } else {
    size_t off = idx8 - WE;
    src = H + off;
    dst = Hb + off;
  }
  float4 a = ((const float4*)src)[0];
  float4 b = ((const float4*)src)[1];
  *(bf16x8*)(short*)dst = cvt8(a, b);
}

// ---------------------------------------------------------------------------
// Kernel 1: pure-bf16 m97-style QKV GEMM (round-5 proven, unchanged).
// C[m,n] = sum_k A[m,k]*W[n,k]. 128x128 tile, BK=32, 4 waves (2x2).
// z<2 -> out [B,H,seq,dh]; z==2 -> out [B,H,dh,seq] (V transposed).
// ---------------------------------------------------------------------------
__global__ void gemm_qkv_bf(const __hip_bfloat16* __restrict__ Hb,
                            const __hip_bfloat16* __restrict__ Wall,
                            __hip_bfloat16* __restrict__ Qw,
                            __hip_bfloat16* __restrict__ Kw,
                            __hip_bfloat16* __restrict__ Vtw) {
  __shared__ __align__(16) __hip_bfloat16 As[128 * 32];
  __shared__ __align__(16) __hip_bfloat16 Bs[128 * 32];
  const int tid = threadIdx.x;
  const int lane = tid & 63;
  const int wave = tid >> 6;
  const int l16 = lane & 15, kq = lane >> 4;
  const int m0 = blockIdx.x * 128, n0 = blockIdx.y * 128;
  const int z = blockIdx.z;
  const __hip_bfloat16* Bm = Wall + (size_t)z * D_DIM * D_DIM;
  const int wr = (wave >> 1) * 64, wc = (wave & 1) * 64;

  f32x4 acc[4][4] = {};

  for (int kk = 0; kk < D_DIM; kk += 32) {
#pragma unroll
    for (int i = 0; i < 2; ++i) {
      int chunk = i * 256 + tid;
      int r = chunk >> 2, c8 = (chunk & 3) << 3;
      int ldsb = (i * 256 + wave * 64) * 16;
      cp16(Hb + (size_t)(m0 + r) * D_DIM + kk + c8, (char*)As + ldsb);
      cp16(Bm + (size_t)(n0 + r) * D_DIM + kk + c8, (char*)Bs + ldsb);
    }
    __syncthreads();
    bf16x8 af[4], bfr[4];
#pragma unroll
    for (int i = 0; i < 4; ++i)
      af[i] = *(const bf16x8*)((const short*)As + (wr + i * 16 + l16) * 32 + kq * 8);
#pragma unroll
    for (int j = 0; j < 4; ++j)
      bfr[j] = *(const bf16x8*)((const short*)Bs + (wc + j * 16 + l16) * 32 + kq * 8);
#pragma unroll
    for (int i = 0; i < 4; ++i)
#pragma unroll
      for (int j = 0; j < 4; ++j)
        acc[i][j] = __builtin_amdgcn_mfma_f32_16x16x32_bf16(af[i], bfr[j], acc[i][j], 0, 0, 0);
    __syncthreads();
  }

  __hip_bfloat16* outp = (z == 0) ? Qw : (z == 1) ? Kw : Vtw;
#pragma unroll
  for (int i = 0; i < 4; ++i) {
#pragma unroll
    for (int r = 0; r < 4; ++r) {
      int gm = m0 + wr + i * 16 + kq * 4 + r;
      int b = gm >> 6, ks = gm & 63;
#pragma unroll
      for (int j = 0; j < 4; ++j) {
        int gn = n0 + wc + j * 16 + l16;
        int h = gn >> 6, dh = gn & 63;
        size_t idx = (z < 2)
            ? ((size_t)(b * NH + h) * SEQ + ks) * DHD + dh
            : ((size_t)(b * NH + h) * DHD + dh) * SEQ + ks;
        outp[idx] = __float2bfloat16(acc[i][j][r]);
      }
    }
  }
}

// ---------------------------------------------------------------------------
// Kernel 2 (v2): attention, ONE HEAD PER WAVE, no __syncthreads.
// K,V,Q fragments loaded from global into registers up front (head K+V=16KB,
// L1-resident). P round-trips through a per-wave private LDS tile (padded
// stride 72 to break bank conflicts); only lgkmcnt waits needed.
// O written in-place into the Q slice (rows written after all Q reads).
// ---------------------------------------------------------------------------
__global__ void attn_v2(__hip_bfloat16* Qw,                 // in: Q, out: O (aliased)
                        const __hip_bfloat16* __restrict__ Kw,
                        const __hip_bfloat16* __restrict__ Vtw,
                        const int* __restrict__ mask) {
  __shared__ __align__(16) __hip_bfloat16 Ps[4][16 * 72];   // 9216 B total
  const int tid = threadIdx.x;
  const int lane = tid & 63;
  const int wave = tid >> 6;
  const int l16 = lane & 15, kq = lane >> 4;                // kq = quad 0..3
  const int hh = blockIdx.x * 4 + wave;                     // head id 0..4095
  const int b = hh >> 4;
  const size_t base = (size_t)hh * 4096;                    // 64x64 slice
  __hip_bfloat16* Pw = &Ps[wave][0];

  // Load all K,V,Q fragments. frag[kk2][j]: rows j*16+l16, cols kk2*32+kq*8.
  bf16x8 kf[2][4], vf[2][4], qf[4][2];
#pragma unroll
  for (int kk2 = 0; kk2 < 2; ++kk2)
#pragma unroll
    for (int j = 0; j < 4; ++j) {
      kf[kk2][j] = *(const bf16x8*)(Kw + base + (j * 16 + l16) * 64 + kk2 * 32 + kq * 8);
      vf[kk2][j] = *(const bf16x8*)(Vtw + base + (j * 16 + l16) * 64 + kk2 * 32 + kq * 8);
    }
#pragma unroll
  for (int qt = 0; qt < 4; ++qt)
#pragma unroll
    for (int kk2 = 0; kk2 < 2; ++kk2)
      qf[qt][kk2] = *(const bf16x8*)(Qw + base + (qt * 16 + l16) * 64 + kk2 * 32 + kq * 8);

#pragma unroll
  for (int qt = 0; qt < 4; ++qt) {
    // S tile: queries qt*16..+15, all 64 keys. q=kq*4+r (rows), s=j*16+l16.
    f32x4 accS[4] = {};
#pragma unroll
    for (int kk2 = 0; kk2 < 2; ++kk2)
#pragma unroll
      for (int j = 0; j < 4; ++j)
        accS[j] = __builtin_amdgcn_mfma_f32_16x16x32_bf16(qf[qt][kk2], kf[kk2][j],
                                                          accS[j], 0, 0, 0);
    // softmax over keys for the 4 rows this lane owns
#pragma unroll
    for (int r = 0; r < 4; ++r) {
      float sv[4];
      float m = -1e30f;
#pragma unroll
      for (int j = 0; j < 4; ++j) { sv[j] = accS[j][r] * ATT_SCALE; m = fmaxf(m, sv[j]); }
#pragma unroll
      for (int off = 1; off < 16; off <<= 1) m = fmaxf(m, __shfl_xor(m, off, 64));
      float s = 0.f;
#pragma unroll
      for (int j = 0; j < 4; ++j) { sv[j] = __expf(sv[j] - m); s += sv[j]; }
#pragma unroll
      for (int off = 1; off < 16; off <<= 1) s += __shfl_xor(s, off, 64);
      float inv = 1.0f / s;
      int ql = kq * 4 + r;                       // local query row 0..15
#pragma unroll
      for (int j = 0; j < 4; ++j)
        Pw[ql * 72 + j * 16 + l16] = __float2bfloat16(sv[j] * inv);
    }
    __asm volatile("s_waitcnt lgkmcnt(0)" ::: "memory");

    // O tile = P @ V: A-frag m=l16 (query), k=kk2*32+kq*8 from padded P.
    f32x4 accO[4] = {};
#pragma unroll
    for (int kk2 = 0; kk2 < 2; ++kk2) {
      bf16x8 a = *(const bf16x8*)((const short*)Pw + l16 * 72 + kk2 * 32 + kq * 8);
#pragma unroll
      for (int j = 0; j < 4; ++j)
        accO[j] = __builtin_amdgcn_mfma_f32_16x16x32_bf16(a, vf[kk2][j], accO[j], 0, 0, 0);
    }
    __asm volatile("s_waitcnt lgkmcnt(0)" ::: "memory");  // P reads done before next qt writes

    // masked store: q = qt*16 + kq*4 + r, d = j*16 + l16
#pragma unroll
    for (int r = 0; r < 4; ++r) {
      int q = qt * 16 + kq * 4 + r;
      float mk = mask[b * SEQ + q] ? 1.0f : 0.0f;
#pragma unroll
      for (int j = 0; j < 4; ++j)
        Qw[base + q * DHD + j * 16 + l16] = __float2bfloat16(accO[j][r] * mk);
    }
  }
}

// ---------------------------------------------------------------------------
// Kernel 3: O projection + gated residual, bf16 residual path.
// Hb(bf16) updated IN-PLACE: Hb = Hb + mask[m]*(O @ Wo^T). Elementwise-safe.
// ---------------------------------------------------------------------------
__global__ void gemm_o(const __hip_bfloat16* __restrict__ Ow,   // [B,H,seq,dh]
                       const __hip_bfloat16* __restrict__ WoB,  // bf16 [1024][1024]
                       const int* __restrict__ mask,
                       __hip_bfloat16* Hb) {                    // residual in/out
  __shared__ __align__(16) __hip_bfloat16 As[128 * 32];
  __shared__ __align__(16) __hip_bfloat16 Bs[128 * 32];
  const int tid = threadIdx.x;
  const int lane = tid & 63;
  const int wave = tid >> 6;
  const int l16 = lane & 15, kq = lane >> 4;
  const int m0 = blockIdx.x * 128, n0 = blockIdx.y * 128;
  const int wr = (wave >> 1) * 64, wc = (wave & 1) * 64;

  f32x4 acc[4][4] = {};

  for (int kk = 0; kk < D_DIM; kk += 32) {
#pragma unroll
    for (int i = 0; i < 2; ++i) {
      int chunk = i * 256 + tid;
      int r = chunk >> 2, c8 = (chunk & 3) << 3;
      int ldsb = (i * 256 + wave * 64) * 16;
      int t = m0 + r, f = kk + c8;
      int b = t >> 6, s = t & 63, h = f >> 6, dh = f & 63;
      cp16(Ow + ((size_t)((b << 4) + h) << 12) + (s << 6) + dh, (char*)As + ldsb);
      cp16(WoB + (size_t)(n0 + r) * D_DIM + kk + c8, (char*)Bs + ldsb);
    }
    __syncthreads();
    bf16x8 af[4], bfr[4];
#pragma unroll
    for (int i = 0; i < 4; ++i)
      af[i] = *(const bf16x8*)((const short*)As + (wr + i * 16 + l16) * 32 + kq * 8);
#pragma unroll
    for (int j = 0; j < 4; ++j)
      bfr[j] = *(const bf16x8*)((const short*)Bs + (wc + j * 16 + l16) * 32 + kq * 8);
#pragma unroll
    for (int i = 0; i < 4; ++i)
#pragma unroll
      for (int j = 0; j < 4; ++j)
        acc[i][j] = __builtin_amdgcn_mfma_f32_16x16x32_bf16(af[i], bfr[j], acc[i][j], 0, 0, 0);
    __syncthreads();
  }

#pragma unroll
  for (int i = 0; i < 4; ++i) {
#pragma unroll
    for (int r = 0; r < 4; ++r) {
      int gm = m0 + wr + i * 16 + kq * 4 + r;
      float mk = mask[gm] ? 1.0f : 0.0f;
#pragma unroll
      for (int j = 0; j < 4; ++j) {
        int gn = n0 + wc + j * 16 + l16;
        size_t idx = (size_t)gm * D_DIM + gn;
        Hb[idx] = __float2bfloat16(__bfloat162float(Hb[idx]) + mk * acc[i][j][r]);
      }
    }
  }
}

// ---------------------------------------------------------------------------
// Kernel 4: LayerNorm over D=1024, bf16 in / fp32 out. One row/block, 128 thr.
// ---------------------------------------------------------------------------
__global__ void ln_bf(const __hip_bfloat16* __restrict__ Hf,
                      const float* __restrict__ gamma,
                      const float* __restrict__ beta,
                      float* __restrict__ out) {
  __shared__ float red[4];
  const int row = blockIdx.x, tid = threadIdx.x;
  const int wave = tid >> 6, lane = tid & 63;
  const size_t boff = (size_t)row * D_DIM + tid * 8;

  bf16x8 v = *(const bf16x8*)((const short*)Hf + boff);
  float f[8], s = 0.f, ss = 0.f;
#pragma unroll
  for (int k = 0; k < 8; ++k) { f[k] = bf2f(v[k]); s += f[k]; ss += f[k] * f[k]; }
#pragma unroll
  for (int off = 1; off < 64; off <<= 1) {
    s += __shfl_xor(s, off, 64);
    ss += __shfl_xor(ss, off, 64);
  }
  if (lane == 0) { red[wave * 2] = s; red[wave * 2 + 1] = ss; }
  __syncthreads();
  s = red[0] + red[2];
  ss = red[1] + red[3];
  const float mu = s * (1.0f / D_DIM);
  const float var = ss * (1.0f / D_DIM) - mu * mu;
  const float rs = rsqrtf(var + LN_EPS);

  float4 g0 = ((const float4*)(gamma + tid * 8))[0];
  float4 g1 = ((const float4*)(gamma + tid * 8))[1];
  float4 b0 = ((const float4*)(beta + tid * 8))[0];
  float4 b1 = ((const float4*)(beta + tid * 8))[1];
  float g[8] = {g0.x, g0.y, g0.z, g0.w, g1.x, g1.y, g1.z, g1.w};
  float bb[8] = {b0.x, b0.y, b0.z, b0.w, b1.x, b1.y, b1.z, b1.w};
  float o[8];
#pragma unroll
  for (int k = 0; k < 8; ++k)
    o[k] = (f[k] - mu) * rs * g[k] + bb[k];
  ((float4*)(out + boff))[0] = make_float4(o[0], o[1], o[2], o[3]);
  ((float4*)(out + boff))[1] = make_float4(o[4], o[5], o[6], o[7]);
}

// ---------------------------------------------------------------------------
extern "C" void kernel_launch(void* const* d_in, const int* in_sizes, int n_in,
                              void* d_out, int out_size, void* d_ws, size_t ws_size,
                              hipStream_t stream) {
  const float* hidden = (const float*)d_in[0];
  const int* mask = (const int*)d_in[1];
  const float* Wq = (const float*)d_in[2];
  const float* Wk = (const float*)d_in[3];
  const float* Wv = (const float*)d_in[4];
  const float* Wo = (const float*)d_in[5];
  const float* gamma = (const float*)d_in[6];
  const float* beta = (const float*)d_in[7];
  float* out = (float*)d_out;

  const size_t SZ = (size_t)M_TOT * D_DIM;        // 16,777,216 elements
  // layout: [Hb][Kw][Qw][Vtw][Wall]  (~142.6 MB, fits per round-5 evidence)
  __hip_bfloat16* Hb   = (__hip_bfloat16*)d_ws;   // bf16 hidden; becomes Hf in-place
  __hip_bfloat16* Kw   = Hb + SZ;
  __hip_bfloat16* Qw   = Hb + 2 * SZ;             // O written in-place by attn
  __hip_bfloat16* Vtw  = Hb + 3 * SZ;
  __hip_bfloat16* Wall = Hb + 4 * SZ;             // bf16 [4][1024][1024]

  conv_all<<<dim3(10240), 256, 0, stream>>>(Wq, Wk, Wv, Wo, hidden, Wall, Hb);
  gemm_qkv_bf<<<dim3(128, 8, 3), 256, 0, stream>>>(Hb, Wall, Qw, Kw, Vtw);
  attn_v2<<<dim3(1024), 256, 0, stream>>>(Qw, Kw, Vtw, mask);
  gemm_o<<<dim3(128, 8), 256, 0, stream>>>(Qw, Wall + 3 * D_DIM * D_DIM, mask, Hb);
  ln_bf<<<dim3(16384), 128, 0, stream>>>(Hb, gamma, beta, out);
}